// Round 6
// baseline (264.188 us; speedup 1.0000x reference)
//
#include <hip/hip_runtime.h>

#define NB 4            // batches
#define NA 120000       // anchors
#define NC 80           // classes
#define NM 32           // annotations per batch

#define EPS_   1e-4f
#define LN2_   0.69314718055994531f

constexpr int BLOCK  = 256;                // 4 waves
constexpr int WPB    = 4;                  // waves per block
constexpr int APW    = 16;                 // anchors per wave per chunk
constexpr int APC    = WPB * APW;          // 64 anchors per block-chunk
constexpr int NCHUNK = NA / APC;           // 1875
constexpr int BPB    = 512;                // persistent blocks per batch (2048 total = 8/CU)
constexpr int BINS   = 64;                 // atomic spreading bins per (batch, quantity)
// d_ws: acc = double[NB*3*BINS] (6144 B); q: 0=cls, 1=reg, 2=pos

__device__ __forceinline__ float wave_reduce_f(float v) {
    #pragma unroll
    for (int off = 32; off > 0; off >>= 1) v += __shfl_down(v, off, 64);
    return v;
}
__device__ __forceinline__ double wave_reduce_d(double v) {
    #pragma unroll
    for (int off = 32; off > 0; off >>= 1) v += __shfl_down(v, off, 64);
    return v;
}

// fast log2 -> v_log_f32 (inputs are clamped well away from denormals)
__device__ __forceinline__ float flog2(float x) { return __builtin_amdgcn_logf(x); }

__global__ __launch_bounds__(BLOCK, 8)
void focal_persist(const float* __restrict__ cls,
                   const float* __restrict__ reg,
                   const float* __restrict__ anchors,
                   const float* __restrict__ ann,
                   double* __restrict__ acc)
{
    __shared__ float s_ann[NM * 10];       // 320 floats, this block's batch
    __shared__ float s_red[3][WPB];

    const int b    = blockIdx.x >> 9;      // 512 blocks per batch
    const int blk  = blockIdx.x & (BPB - 1);
    const int tid  = threadIdx.x;
    const int wave = tid >> 6;
    const int lane = tid & 63;
    const int aloc = lane >> 2;            // anchor within wave's 16
    const int part = lane & 3;             // which 8-annotation slice this lane scans

    // stage this batch's annotations once; the chunk loop below is barrier-free
    s_ann[tid < NM * 10 ? tid : 0] = ann[b * NM * 10 + (tid < NM * 10 ? tid : 0)];
    if (tid < NM * 10 - BLOCK) s_ann[BLOCK + tid] = ann[b * NM * 10 + BLOCK + tid];
    __syncthreads();

    float clsSum = 0.0f, regLoss = 0.0f, posCnt = 0.0f;

    const float4* anchors4 = (const float4*)anchors;
    const float4* cls4b    = (const float4*)cls + (size_t)b * NA * (NC / 4);

    for (int c = blk; c < NCHUNK; c += BPB) {
        const int aw0 = c * APC + wave * APW;      // this wave's first anchor
        const int a   = aw0 + aloc;                // this lane's anchor (4 lanes share it)

        // ---- issue all global loads up front (anchor first: it's on the meta path) --
        const float4 an = anchors4[a];
        const float4* w4 = cls4b + (size_t)aw0 * (NC / 4);   // wave's 320 float4
        float4 x0 = w4[lane];
        float4 x1 = w4[lane + 64];
        float4 x2 = w4[lane + 128];
        float4 x3 = w4[lane + 192];
        float4 x4_ = w4[lane + 256];

        // ---- meta: 8 IoUs per lane, shfl_xor argmax merge over the 4 parts --------
        const float ax1 = an.x, ay1 = an.y, ax2 = an.z, ay2 = an.w;
        const float aw_ = ax2 - ax1, ah = ay2 - ay1;
        const float acx = ax1 + 0.5f * aw_, acy = ay1 + 0.5f * ah;
        const float areaA = aw_ * ah;

        float best = -1.0f;
        int   arg  = 0;
        #pragma unroll
        for (int i = 0; i < 8; ++i) {
            const int m = part * 8 + i;            // ascending within part -> first-max
            const float bx1 = s_ann[m * 10 + 4];
            const float by1 = s_ann[m * 10 + 5];
            const float bx2 = s_ann[m * 10 + 6];
            const float by2 = s_ann[m * 10 + 7];
            float iw = fminf(ax2, bx2) - fmaxf(ax1, bx1); iw = fmaxf(iw, 0.0f);
            float ih = fminf(ay2, by2) - fmaxf(ay1, by1); ih = fmaxf(ih, 0.0f);
            const float inter = iw * ih;
            const float areaB = (bx2 - bx1) * (by2 - by1);
            const float ua    = fmaxf(areaA + areaB - inter, 1e-8f);
            const float iou   = inter / ua;
            if (iou > best) { best = iou; arg = m; }
        }
        #pragma unroll
        for (int d = 1; d <= 2; d <<= 1) {         // merge parts; tie -> lower index
            const float ob = __shfl_xor(best, d, 64);
            const int   oa = __shfl_xor(arg,  d, 64);
            if (ob > best || (ob == best && oa < arg)) { best = ob; arg = oa; }
        }

        const bool pos = best >= 0.5f;
        const bool neg = best < 0.4f;
        const float coefL = (pos || neg) ? (-0.25f * LN2_) : 0.0f;

        if (pos && part == 0) {                    // rare path, one lane per anchor
            posCnt += 1.0f;
            const int cc = (int)s_ann[arg * 10 + 8];
            // correction: replace neg-term with pos-term at the assigned class
            const float xc = cls[((size_t)b * NA + a) * NC + cc];
            const float p  = fminf(fmaxf(xc, EPS_), 1.0f - EPS_);
            const float q  = 1.0f - p;
            clsSum += 0.75f * q * q * (-LN2_ * flog2(p))
                    - 0.25f * p * p * (-LN2_ * flog2(q));

            // regression loss: only components 0..3 (full box) survive the mask
            const float fx1 = s_ann[arg * 10 + 4];
            const float fy1 = s_ann[arg * 10 + 5];
            const float fx2 = s_ann[arg * 10 + 6];
            const float fy2 = s_ann[arg * 10 + 7];
            float gw = fx2 - fx1, gh = fy2 - fy1;
            const float gcx = fx1 + 0.5f * gw, gcy = fy1 + 0.5f * gh; // pre-clip centers
            gw = fmaxf(gw, 1.0f); gh = fmaxf(gh, 1.0f);
            const float t0 = ((gcx - acx) / aw_) * 10.0f;
            const float t1 = ((gcy - acy) / ah)  * 10.0f;
            const float t2 = (LN2_ * flog2(gw / aw_)) * 5.0f;
            const float t3 = (LN2_ * flog2(gh / ah))  * 5.0f;
            const float4 r4 = ((const float4*)reg)[(size_t)(b * NA + a) * 2];
            const float d0 = fabsf(t0 - r4.x);
            const float d1 = fabsf(t1 - r4.y);
            const float d2 = fabsf(t2 - r4.z);
            const float d3 = fabsf(t3 - r4.w);
            const float beta = 1.0f / 9.0f;
            #define SL1(d) ((d) <= beta ? 4.5f * (d) * (d) : (d) - 0.5f / 9.0f)
            regLoss += SL1(d0) + SL1(d1) + SL1(d2) + SL1(d3);
            #undef SL1
        }

        // ---- consume: branch-free neg-term sweep, coef via register shfl -----------
        #define TERM(XV, J)                                                      \
        {                                                                        \
            const int idx = lane + 64 * (J);                                     \
            const float C = __shfl(coefL, (idx / (NC / 4)) << 2, 64);            \
            float p0 = fminf(fmaxf((XV).x, EPS_), 1.0f - EPS_);                  \
            float p1 = fminf(fmaxf((XV).y, EPS_), 1.0f - EPS_);                  \
            float p2 = fminf(fmaxf((XV).z, EPS_), 1.0f - EPS_);                  \
            float p3 = fminf(fmaxf((XV).w, EPS_), 1.0f - EPS_);                  \
            float t0 = p0 * p0 * flog2(1.0f - p0);                               \
            float t1 = p1 * p1 * flog2(1.0f - p1);                               \
            float t2 = p2 * p2 * flog2(1.0f - p2);                               \
            float t3 = p3 * p3 * flog2(1.0f - p3);                               \
            clsSum = fmaf((t0 + t1) + (t2 + t3), C, clsSum);                     \
        }
        TERM(x0, 0) TERM(x1, 1) TERM(x2, 2) TERM(x3, 3) TERM(x4_, 4)
        #undef TERM
    }

    // ---- block reduce -> binned double atomics ------------------------------------
    float rc = wave_reduce_f(clsSum);
    float rr = wave_reduce_f(regLoss);
    float rp = wave_reduce_f(posCnt);
    if (lane == 0) { s_red[0][wave] = rc; s_red[1][wave] = rr; s_red[2][wave] = rp; }
    __syncthreads();
    if (tid == 0) {
        const float c = (s_red[0][0] + s_red[0][1]) + (s_red[0][2] + s_red[0][3]);
        const float r = (s_red[1][0] + s_red[1][1]) + (s_red[1][2] + s_red[1][3]);
        const float p = (s_red[2][0] + s_red[2][1]) + (s_red[2][2] + s_red[2][3]);
        const int bin = blockIdx.x & (BINS - 1);
        atomicAdd(&acc[(b * 3 + 0) * BINS + bin], (double)c);
        atomicAdd(&acc[(b * 3 + 1) * BINS + bin], (double)r);
        atomicAdd(&acc[(b * 3 + 2) * BINS + bin], (double)p);
    }
}

__global__ void focal_finalize(const double* __restrict__ acc, float* __restrict__ out) {
    __shared__ double g[NB * 3];
    const int tid  = threadIdx.x;          // 768 threads = 12 waves, one per (b,q)
    const int wave = tid >> 6, lane = tid & 63;
    double v = acc[wave * BINS + lane];
    v = wave_reduce_d(v);
    if (lane == 0) g[wave] = v;
    __syncthreads();
    if (tid == 0) {
        double clsTot = 0.0, regTot = 0.0;
        #pragma unroll
        for (int b = 0; b < NB; ++b) {
            const double np  = g[b * 3 + 2];
            const double npc = np < 1.0 ? 1.0 : np;
            clsTot += g[b * 3 + 0] / npc;
            regTot += (np > 0.0) ? g[b * 3 + 1] / (npc * 4.0) : 0.0;
        }
        out[0] = (float)(clsTot / NB);
        out[1] = (float)(regTot / NB);
    }
}

extern "C" void kernel_launch(void* const* d_in, const int* in_sizes, int n_in,
                              void* d_out, int out_size, void* d_ws, size_t ws_size,
                              hipStream_t stream) {
    const float* cls     = (const float*)d_in[0];   // (B, A, C)
    const float* reg     = (const float*)d_in[1];   // (B, A, 8)
    const float* anchors = (const float*)d_in[2];   // (1, A, 4)
    const float* ann     = (const float*)d_in[3];   // (B, M, 10)
    float* out  = (float*)d_out;
    double* acc = (double*)d_ws;                    // 768 doubles

    hipMemsetAsync(acc, 0, NB * 3 * BINS * sizeof(double), stream);

    focal_persist<<<NB * BPB, BLOCK, 0, stream>>>(cls, reg, anchors, ann, acc);
    focal_finalize<<<1, NB * 3 * BINS, 0, stream>>>(acc, out);
}

// Round 7
// 232.674 us; speedup vs baseline: 1.1354x; 1.1354x over previous
//
#include <hip/hip_runtime.h>

#define NB 4            // batches
#define NA 120000       // anchors
#define NC 80           // classes
#define NM 32           // annotations per batch

#define EPS_   1e-4f
#define LN2_   0.69314718055994531f

constexpr int BLOCK  = 256;                // 4 waves
constexpr int WPB    = 4;                  // waves per block
constexpr int APW    = 16;                 // anchors per wave per chunk
constexpr int APC    = WPB * APW;          // 64 anchors per block-chunk
constexpr int NCHUNK = NA / APC;           // 1875
constexpr int BPB    = 512;                // blocks per batch (2048 total)
constexpr int BINS   = 64;                 // atomic spreading bins per (batch, quantity)
// d_ws: acc = double[NB*3*BINS] (6144 B); q: 0=cls, 1=reg, 2=pos

__device__ __forceinline__ float wave_reduce_f(float v) {
    #pragma unroll
    for (int off = 32; off > 0; off >>= 1) v += __shfl_down(v, off, 64);
    return v;
}
__device__ __forceinline__ double wave_reduce_d(double v) {
    #pragma unroll
    for (int off = 32; off > 0; off >>= 1) v += __shfl_down(v, off, 64);
    return v;
}

// fast log2 -> v_log_f32 (inputs are clamped well away from denormals)
__device__ __forceinline__ float flog2(float x) { return __builtin_amdgcn_logf(x); }

// (256, 4): 128-VGPR cap. R6 used (256, 8) -> 64-VGPR cap -> the compiler
// spilled the 5-float4 streaming payload to scratch (WRITE_SIZE 80 MB, 2.6 TB/s).
// MLP needs registers, not waves: 16 waves/CU x 5 KiB in-flight/wave >> Little's-law need.
__global__ __launch_bounds__(BLOCK, 4)
void focal_persist(const float* __restrict__ cls,
                   const float* __restrict__ reg,
                   const float* __restrict__ anchors,
                   const float* __restrict__ ann,
                   double* __restrict__ acc)
{
    __shared__ float s_ann[NM * 10];       // 320 floats, this block's batch
    __shared__ float s_red[3][WPB];

    const int b    = blockIdx.x >> 9;      // 512 blocks per batch
    const int blk  = blockIdx.x & (BPB - 1);
    const int tid  = threadIdx.x;
    const int wave = tid >> 6;
    const int lane = tid & 63;
    const int aloc = lane >> 2;            // anchor within wave's 16
    const int part = lane & 3;             // which 8-annotation slice this lane scans

    // stage this batch's annotations once; the chunk loop below is barrier-free
    s_ann[tid] = ann[b * NM * 10 + tid];                               // tid < 320 always
    if (tid < NM * 10 - BLOCK) s_ann[BLOCK + tid] = ann[b * NM * 10 + BLOCK + tid];
    __syncthreads();

    float clsSum = 0.0f, regLoss = 0.0f, posCnt = 0.0f;

    const float4* anchors4 = (const float4*)anchors;
    const float4* cls4b    = (const float4*)cls + (size_t)b * NA * (NC / 4);

    for (int c = blk; c < NCHUNK; c += BPB) {
        const int aw0 = c * APC + wave * APW;      // this wave's first anchor
        const int a   = aw0 + aloc;                // this lane's anchor (4 lanes share it)

        // ---- issue all global loads up front (anchor first: it's on the meta path) --
        const float4 an = anchors4[a];
        const float4* w4 = cls4b + (size_t)aw0 * (NC / 4);   // wave's 320 float4
        float4 x0 = w4[lane];
        float4 x1 = w4[lane + 64];
        float4 x2 = w4[lane + 128];
        float4 x3 = w4[lane + 192];
        float4 x4_ = w4[lane + 256];

        // ---- meta: 8 IoUs per lane, shfl_xor argmax merge over the 4 parts --------
        const float ax1 = an.x, ay1 = an.y, ax2 = an.z, ay2 = an.w;
        const float aw_ = ax2 - ax1, ah = ay2 - ay1;
        const float acx = ax1 + 0.5f * aw_, acy = ay1 + 0.5f * ah;
        const float areaA = aw_ * ah;

        float best = -1.0f;
        int   arg  = 0;
        #pragma unroll
        for (int i = 0; i < 8; ++i) {
            const int m = part * 8 + i;            // ascending within part -> first-max
            const float bx1 = s_ann[m * 10 + 4];
            const float by1 = s_ann[m * 10 + 5];
            const float bx2 = s_ann[m * 10 + 6];
            const float by2 = s_ann[m * 10 + 7];
            float iw = fminf(ax2, bx2) - fmaxf(ax1, bx1); iw = fmaxf(iw, 0.0f);
            float ih = fminf(ay2, by2) - fmaxf(ay1, by1); ih = fmaxf(ih, 0.0f);
            const float inter = iw * ih;
            const float areaB = (bx2 - bx1) * (by2 - by1);
            const float ua    = fmaxf(areaA + areaB - inter, 1e-8f);
            const float iou   = inter / ua;
            if (iou > best) { best = iou; arg = m; }
        }
        #pragma unroll
        for (int d = 1; d <= 2; d <<= 1) {         // merge parts; tie -> lower index
            const float ob = __shfl_xor(best, d, 64);
            const int   oa = __shfl_xor(arg,  d, 64);
            if (ob > best || (ob == best && oa < arg)) { best = ob; arg = oa; }
        }

        const bool pos = best >= 0.5f;
        const bool neg = best < 0.4f;
        const float coefL = (pos || neg) ? (-0.25f * LN2_) : 0.0f;

        if (pos && part == 0) {                    // rare path, one lane per anchor
            posCnt += 1.0f;
            const int cc = (int)s_ann[arg * 10 + 8];
            // correction: replace neg-term with pos-term at the assigned class
            const float xc = cls[((size_t)b * NA + a) * NC + cc];
            const float p  = fminf(fmaxf(xc, EPS_), 1.0f - EPS_);
            const float q  = 1.0f - p;
            clsSum += 0.75f * q * q * (-LN2_ * flog2(p))
                    - 0.25f * p * p * (-LN2_ * flog2(q));

            // regression loss: only components 0..3 (full box) survive the mask
            const float fx1 = s_ann[arg * 10 + 4];
            const float fy1 = s_ann[arg * 10 + 5];
            const float fx2 = s_ann[arg * 10 + 6];
            const float fy2 = s_ann[arg * 10 + 7];
            float gw = fx2 - fx1, gh = fy2 - fy1;
            const float gcx = fx1 + 0.5f * gw, gcy = fy1 + 0.5f * gh; // pre-clip centers
            gw = fmaxf(gw, 1.0f); gh = fmaxf(gh, 1.0f);
            const float t0 = ((gcx - acx) / aw_) * 10.0f;
            const float t1 = ((gcy - acy) / ah)  * 10.0f;
            const float t2 = (LN2_ * flog2(gw / aw_)) * 5.0f;
            const float t3 = (LN2_ * flog2(gh / ah))  * 5.0f;
            const float4 r4 = ((const float4*)reg)[(size_t)(b * NA + a) * 2];
            const float d0 = fabsf(t0 - r4.x);
            const float d1 = fabsf(t1 - r4.y);
            const float d2 = fabsf(t2 - r4.z);
            const float d3 = fabsf(t3 - r4.w);
            const float beta = 1.0f / 9.0f;
            #define SL1(d) ((d) <= beta ? 4.5f * (d) * (d) : (d) - 0.5f / 9.0f)
            regLoss += SL1(d0) + SL1(d1) + SL1(d2) + SL1(d3);
            #undef SL1
        }

        // ---- consume: branch-free neg-term sweep, coef via register shfl -----------
        #define TERM(XV, J)                                                      \
        {                                                                        \
            const int idx = lane + 64 * (J);                                     \
            const float C = __shfl(coefL, (idx / (NC / 4)) << 2, 64);            \
            float p0 = fminf(fmaxf((XV).x, EPS_), 1.0f - EPS_);                  \
            float p1 = fminf(fmaxf((XV).y, EPS_), 1.0f - EPS_);                  \
            float p2 = fminf(fmaxf((XV).z, EPS_), 1.0f - EPS_);                  \
            float p3 = fminf(fmaxf((XV).w, EPS_), 1.0f - EPS_);                  \
            float t0 = p0 * p0 * flog2(1.0f - p0);                               \
            float t1 = p1 * p1 * flog2(1.0f - p1);                               \
            float t2 = p2 * p2 * flog2(1.0f - p2);                               \
            float t3 = p3 * p3 * flog2(1.0f - p3);                               \
            clsSum = fmaf((t0 + t1) + (t2 + t3), C, clsSum);                     \
        }
        TERM(x0, 0) TERM(x1, 1) TERM(x2, 2) TERM(x3, 3) TERM(x4_, 4)
        #undef TERM
    }

    // ---- block reduce -> binned double atomics ------------------------------------
    float rc = wave_reduce_f(clsSum);
    float rr = wave_reduce_f(regLoss);
    float rp = wave_reduce_f(posCnt);
    if (lane == 0) { s_red[0][wave] = rc; s_red[1][wave] = rr; s_red[2][wave] = rp; }
    __syncthreads();
    if (tid == 0) {
        const float c = (s_red[0][0] + s_red[0][1]) + (s_red[0][2] + s_red[0][3]);
        const float r = (s_red[1][0] + s_red[1][1]) + (s_red[1][2] + s_red[1][3]);
        const float p = (s_red[2][0] + s_red[2][1]) + (s_red[2][2] + s_red[2][3]);
        const int bin = blockIdx.x & (BINS - 1);
        atomicAdd(&acc[(b * 3 + 0) * BINS + bin], (double)c);
        atomicAdd(&acc[(b * 3 + 1) * BINS + bin], (double)r);
        atomicAdd(&acc[(b * 3 + 2) * BINS + bin], (double)p);
    }
}

__global__ void focal_finalize(const double* __restrict__ acc, float* __restrict__ out) {
    __shared__ double g[NB * 3];
    const int tid  = threadIdx.x;          // 768 threads = 12 waves, one per (b,q)
    const int wave = tid >> 6, lane = tid & 63;
    double v = acc[wave * BINS + lane];
    v = wave_reduce_d(v);
    if (lane == 0) g[wave] = v;
    __syncthreads();
    if (tid == 0) {
        double clsTot = 0.0, regTot = 0.0;
        #pragma unroll
        for (int b = 0; b < NB; ++b) {
            const double np  = g[b * 3 + 2];
            const double npc = np < 1.0 ? 1.0 : np;
            clsTot += g[b * 3 + 0] / npc;
            regTot += (np > 0.0) ? g[b * 3 + 1] / (npc * 4.0) : 0.0;
        }
        out[0] = (float)(clsTot / NB);
        out[1] = (float)(regTot / NB);
    }
}

extern "C" void kernel_launch(void* const* d_in, const int* in_sizes, int n_in,
                              void* d_out, int out_size, void* d_ws, size_t ws_size,
                              hipStream_t stream) {
    const float* cls     = (const float*)d_in[0];   // (B, A, C)
    const float* reg     = (const float*)d_in[1];   // (B, A, 8)
    const float* anchors = (const float*)d_in[2];   // (1, A, 4)
    const float* ann     = (const float*)d_in[3];   // (B, M, 10)
    float* out  = (float*)d_out;
    double* acc = (double*)d_ws;                    // 768 doubles

    hipMemsetAsync(acc, 0, NB * 3 * BINS * sizeof(double), stream);

    focal_persist<<<NB * BPB, BLOCK, 0, stream>>>(cls, reg, anchors, ann, acc);
    focal_finalize<<<1, NB * 3 * BINS, 0, stream>>>(acc, out);
}

// Round 8
// 232.619 us; speedup vs baseline: 1.1357x; 1.0002x over previous
//
#include <hip/hip_runtime.h>

#define NB 4            // batches
#define NA 120000       // anchors
#define NC 80           // classes
#define NM 32           // annotations per batch

#define EPS_   1e-4f
#define LN2_   0.69314718055994531f

constexpr int BLOCK  = 256;                // 4 waves
constexpr int WPB    = 4;                  // waves per block
constexpr int APW    = 16;                 // anchors per wave per chunk
constexpr int APC    = WPB * APW;          // 64 anchors per block-chunk
constexpr int NCHUNK = NA / APC;           // 1875
constexpr int BPB    = 512;                // blocks per batch (2048 total)
constexpr int BINS   = 64;                 // atomic spreading bins per (batch, quantity)
constexpr int QCAP   = 256;                // max pos anchors per block (4 chunks x 64) - provably safe
// d_ws: acc = double[NB*3*BINS] (6144 B); q: 0=cls, 1=reg, 2=pos

__device__ __forceinline__ float wave_reduce_f(float v) {
    #pragma unroll
    for (int off = 32; off > 0; off >>= 1) v += __shfl_down(v, off, 64);
    return v;
}
__device__ __forceinline__ double wave_reduce_d(double v) {
    #pragma unroll
    for (int off = 32; off > 0; off >>= 1) v += __shfl_down(v, off, 64);
    return v;
}

// fast log2 -> v_log_f32 (inputs are clamped well away from denormals)
__device__ __forceinline__ float flog2(float x) { return __builtin_amdgcn_logf(x); }

// (256,4): 128-VGPR cap. (256,8)'s 64-VGPR cap spilled the payload (R6: WRITE_SIZE 80MB).
__global__ __launch_bounds__(BLOCK, 4)
void focal_persist(const float* __restrict__ cls,
                   const float* __restrict__ reg,
                   const float* __restrict__ anchors,
                   const float* __restrict__ ann,
                   double* __restrict__ acc)
{
    __shared__ float s_ann[NM * 10];       // 320 floats, this block's batch
    __shared__ float s_red[2][WPB];
    __shared__ int   s_q[QCAP];            // deferred pos anchors: (a<<5)|arg
    __shared__ int   s_qn;

    const int b    = blockIdx.x >> 9;      // 512 blocks per batch
    const int blk  = blockIdx.x & (BPB - 1);
    const int tid  = threadIdx.x;
    const int wave = tid >> 6;
    const int lane = tid & 63;
    const int aloc = lane >> 2;            // anchor within wave's 16
    const int part = lane & 3;             // which 8-annotation slice this lane scans

    if (tid == 0) s_qn = 0;
    s_ann[tid] = ann[b * NM * 10 + tid];   // 0..255
    if (tid < NM * 10 - BLOCK) s_ann[BLOCK + tid] = ann[b * NM * 10 + BLOCK + tid];
    __syncthreads();

    float clsSum = 0.0f, regLoss = 0.0f;

    const float4* anchors4 = (const float4*)anchors;
    const float4* cls4b    = (const float4*)cls + (size_t)b * NA * (NC / 4);

    // -------- software pipeline, depth 2: prefetch chunk c+BPB while consuming c ----
    int c = blk;
    float4 an0, x0, x1, x2, x3, x4_;
    {
        const int aw0 = c * APC + wave * APW;
        an0 = anchors4[aw0 + aloc];
        const float4* w4 = cls4b + (size_t)aw0 * (NC / 4);
        x0 = w4[lane]; x1 = w4[lane + 64]; x2 = w4[lane + 128];
        x3 = w4[lane + 192]; x4_ = w4[lane + 256];
    }

    while (c < NCHUNK) {
        const int cn = c + BPB;
        // last iteration: clamp prefetch to the current chunk (L1/L2-hot, no HBM cost)
        const int cl  = (cn < NCHUNK) ? cn : c;
        const int nw0 = cl * APC + wave * APW;
        const float4 an1 = anchors4[nw0 + aloc];
        const float4* v4 = cls4b + (size_t)nw0 * (NC / 4);
        const float4 y0 = v4[lane], y1 = v4[lane + 64], y2 = v4[lane + 128];
        const float4 y3 = v4[lane + 192], y4 = v4[lane + 256];

        // ---- meta: 8 IoUs per lane, shfl_xor argmax merge over the 4 parts --------
        const int a = c * APC + wave * APW + aloc;   // this lane's anchor
        const float ax1 = an0.x, ay1 = an0.y, ax2 = an0.z, ay2 = an0.w;
        const float areaA = (ax2 - ax1) * (ay2 - ay1);

        float best = -1.0f;
        int   arg  = 0;
        #pragma unroll
        for (int i = 0; i < 8; ++i) {
            const int m = part * 8 + i;            // ascending within part -> first-max
            const float bx1 = s_ann[m * 10 + 4];
            const float by1 = s_ann[m * 10 + 5];
            const float bx2 = s_ann[m * 10 + 6];
            const float by2 = s_ann[m * 10 + 7];
            float iw = fminf(ax2, bx2) - fmaxf(ax1, bx1); iw = fmaxf(iw, 0.0f);
            float ih = fminf(ay2, by2) - fmaxf(ay1, by1); ih = fmaxf(ih, 0.0f);
            const float inter = iw * ih;
            const float areaB = (bx2 - bx1) * (by2 - by1);
            const float ua    = fmaxf(areaA + areaB - inter, 1e-8f);
            const float iou   = inter / ua;
            if (iou > best) { best = iou; arg = m; }
        }
        #pragma unroll
        for (int d = 1; d <= 2; d <<= 1) {         // merge parts; tie -> lower index
            const float ob = __shfl_xor(best, d, 64);
            const int   oa = __shfl_xor(arg,  d, 64);
            if (ob > best || (ob == best && oa < arg)) { best = ob; arg = oa; }
        }

        const bool pos = best >= 0.5f;
        const bool neg = best < 0.4f;
        const float coefL = (pos || neg) ? (-0.25f * LN2_) : 0.0f;

        // defer pos-anchor work: LDS queue push only (no global loads in hot loop)
        if (pos && part == 0) {
            const int slot = atomicAdd(&s_qn, 1);
            s_q[slot] = (a << 5) | arg;
        }

        // ---- consume: branch-free neg-term sweep, coef via register shfl -----------
        #define TERM(XV, J)                                                      \
        {                                                                        \
            const int idx = lane + 64 * (J);                                     \
            const float C = __shfl(coefL, (idx / (NC / 4)) << 2, 64);            \
            float p0 = fminf(fmaxf((XV).x, EPS_), 1.0f - EPS_);                  \
            float p1 = fminf(fmaxf((XV).y, EPS_), 1.0f - EPS_);                  \
            float p2 = fminf(fmaxf((XV).z, EPS_), 1.0f - EPS_);                  \
            float p3 = fminf(fmaxf((XV).w, EPS_), 1.0f - EPS_);                  \
            float t0 = p0 * p0 * flog2(1.0f - p0);                               \
            float t1 = p1 * p1 * flog2(1.0f - p1);                               \
            float t2 = p2 * p2 * flog2(1.0f - p2);                               \
            float t3 = p3 * p3 * flog2(1.0f - p3);                               \
            clsSum = fmaf((t0 + t1) + (t2 + t3), C, clsSum);                     \
        }
        TERM(x0, 0) TERM(x1, 1) TERM(x2, 2) TERM(x3, 3) TERM(x4_, 4)
        #undef TERM

        // rotate pipeline
        c = cn;
        an0 = an1; x0 = y0; x1 = y1; x2 = y2; x3 = y3; x4_ = y4;
    }

    // -------- deferred pos-anchor processing: batched, parallel, off the hot path ---
    __syncthreads();                       // queue pushes + s_qn visible block-wide
    const int qn = s_qn;
    if (tid < qn) {
        const int e = s_q[tid];
        const int a = e >> 5;
        const int m = e & 31;

        const float4 an = anchors4[a];
        const float aw_ = an.z - an.x, ah = an.w - an.y;
        const float acx = an.x + 0.5f * aw_, acy = an.y + 0.5f * ah;

        const int cc = (int)s_ann[m * 10 + 8];
        const float xc = cls[((size_t)b * NA + a) * NC + cc];
        const float p  = fminf(fmaxf(xc, EPS_), 1.0f - EPS_);
        const float q  = 1.0f - p;
        clsSum += 0.75f * q * q * (-LN2_ * flog2(p))
                - 0.25f * p * p * (-LN2_ * flog2(q));

        const float fx1 = s_ann[m * 10 + 4];
        const float fy1 = s_ann[m * 10 + 5];
        const float fx2 = s_ann[m * 10 + 6];
        const float fy2 = s_ann[m * 10 + 7];
        float gw = fx2 - fx1, gh = fy2 - fy1;
        const float gcx = fx1 + 0.5f * gw, gcy = fy1 + 0.5f * gh;  // pre-clip centers
        gw = fmaxf(gw, 1.0f); gh = fmaxf(gh, 1.0f);
        const float t0 = ((gcx - acx) / aw_) * 10.0f;
        const float t1 = ((gcy - acy) / ah)  * 10.0f;
        const float t2 = (LN2_ * flog2(gw / aw_)) * 5.0f;
        const float t3 = (LN2_ * flog2(gh / ah))  * 5.0f;
        const float4 r4 = ((const float4*)reg)[(size_t)(b * NA + a) * 2];
        const float d0 = fabsf(t0 - r4.x);
        const float d1 = fabsf(t1 - r4.y);
        const float d2 = fabsf(t2 - r4.z);
        const float d3 = fabsf(t3 - r4.w);
        const float beta = 1.0f / 9.0f;
        #define SL1(d) ((d) <= beta ? 4.5f * (d) * (d) : (d) - 0.5f / 9.0f)
        regLoss = SL1(d0) + SL1(d1) + SL1(d2) + SL1(d3);
        #undef SL1
    }

    // ---- block reduce -> binned double atomics ------------------------------------
    float rc = wave_reduce_f(clsSum);
    float rr = wave_reduce_f(regLoss);
    if (lane == 0) { s_red[0][wave] = rc; s_red[1][wave] = rr; }
    __syncthreads();
    if (tid == 0) {
        const float cs = (s_red[0][0] + s_red[0][1]) + (s_red[0][2] + s_red[0][3]);
        const float rs = (s_red[1][0] + s_red[1][1]) + (s_red[1][2] + s_red[1][3]);
        const int bin = blockIdx.x & (BINS - 1);
        atomicAdd(&acc[(b * 3 + 0) * BINS + bin], (double)cs);
        atomicAdd(&acc[(b * 3 + 1) * BINS + bin], (double)rs);
        atomicAdd(&acc[(b * 3 + 2) * BINS + bin], (double)qn);
    }
}

__global__ void focal_finalize(const double* __restrict__ acc, float* __restrict__ out) {
    __shared__ double g[NB * 3];
    const int tid  = threadIdx.x;          // 768 threads = 12 waves, one per (b,q)
    const int wave = tid >> 6, lane = tid & 63;
    double v = acc[wave * BINS + lane];
    v = wave_reduce_d(v);
    if (lane == 0) g[wave] = v;
    __syncthreads();
    if (tid == 0) {
        double clsTot = 0.0, regTot = 0.0;
        #pragma unroll
        for (int b = 0; b < NB; ++b) {
            const double np  = g[b * 3 + 2];
            const double npc = np < 1.0 ? 1.0 : np;
            clsTot += g[b * 3 + 0] / npc;
            regTot += (np > 0.0) ? g[b * 3 + 1] / (npc * 4.0) : 0.0;
        }
        out[0] = (float)(clsTot / NB);
        out[1] = (float)(regTot / NB);
    }
}

extern "C" void kernel_launch(void* const* d_in, const int* in_sizes, int n_in,
                              void* d_out, int out_size, void* d_ws, size_t ws_size,
                              hipStream_t stream) {
    const float* cls     = (const float*)d_in[0];   // (B, A, C)
    const float* reg     = (const float*)d_in[1];   // (B, A, 8)
    const float* anchors = (const float*)d_in[2];   // (1, A, 4)
    const float* ann     = (const float*)d_in[3];   // (B, M, 10)
    float* out  = (float*)d_out;
    double* acc = (double*)d_ws;                    // 768 doubles

    hipMemsetAsync(acc, 0, NB * 3 * BINS * sizeof(double), stream);

    focal_persist<<<NB * BPB, BLOCK, 0, stream>>>(cls, reg, anchors, ann, acc);
    focal_finalize<<<1, NB * 3 * BINS, 0, stream>>>(acc, out);
}

// Round 9
// 224.159 us; speedup vs baseline: 1.1786x; 1.0377x over previous
//
#include <hip/hip_runtime.h>

#define NB 4            // batches
#define NA 120000       // anchors
#define NC 80           // classes
#define NM 32           // annotations per batch

#define EPS_   1e-4f
#define LN2_   0.69314718055994531f

constexpr int BLOCK  = 256;                // 4 waves
constexpr int WPB    = 4;                  // waves per block
constexpr int APW    = 16;                 // anchors per wave per chunk
constexpr int APC    = WPB * APW;          // 64 anchors per block-chunk
constexpr int NCHUNK = NA / APC;           // 1875
constexpr int BPB    = 512;                // blocks per batch (2048 total)
constexpr int QCAP   = 256;                // max pos anchors per block (4 chunks x 64) - safe
// d_ws: partials = float4[NB*BPB] (32 KB), one per block, PLAIN stores (no memset needed:
// every slot is unconditionally overwritten every launch, so 0xAA poison is harmless)

typedef __attribute__((ext_vector_type(4))) float f32x4;

__device__ __forceinline__ f32x4 nt_load4(const f32x4* p) {
    // read-once stream: 'nt' bypasses L1/L2 allocation -> no thrash of the 32MB L2
    return __builtin_nontemporal_load(p);
}

__device__ __forceinline__ float wave_reduce_f(float v) {
    #pragma unroll
    for (int off = 32; off > 0; off >>= 1) v += __shfl_down(v, off, 64);
    return v;
}
__device__ __forceinline__ double wave_reduce_d(double v) {
    #pragma unroll
    for (int off = 32; off > 0; off >>= 1) v += __shfl_down(v, off, 64);
    return v;
}

// fast log2 -> v_log_f32 (inputs are clamped well away from denormals)
__device__ __forceinline__ float flog2(float x) { return __builtin_amdgcn_logf(x); }

// (256,4): 128-VGPR cap. (256,8)'s 64-VGPR cap spilled the payload (R6: WRITE_SIZE 80MB).
__global__ __launch_bounds__(BLOCK, 4)
void focal_persist(const float* __restrict__ cls,
                   const float* __restrict__ reg,
                   const float* __restrict__ anchors,
                   const float* __restrict__ ann,
                   float4* __restrict__ partials)
{
    __shared__ float s_ann[NM * 10];       // 320 floats, this block's batch
    __shared__ float s_red[2][WPB];
    __shared__ int   s_q[QCAP];            // deferred pos anchors: (a<<5)|arg
    __shared__ int   s_qn;

    const int b    = blockIdx.x >> 9;      // 512 blocks per batch
    const int blk  = blockIdx.x & (BPB - 1);
    const int tid  = threadIdx.x;
    const int wave = tid >> 6;
    const int lane = tid & 63;
    const int aloc = lane >> 2;            // anchor within wave's 16
    const int part = lane & 3;             // which 8-annotation slice this lane scans

    if (tid == 0) s_qn = 0;
    s_ann[tid] = ann[b * NM * 10 + tid];   // 0..255
    if (tid < NM * 10 - BLOCK) s_ann[BLOCK + tid] = ann[b * NM * 10 + BLOCK + tid];
    __syncthreads();

    float clsSum = 0.0f, regLoss = 0.0f;

    const float4* anchors4 = (const float4*)anchors;
    const f32x4*  cls4b    = (const f32x4*)cls + (size_t)b * NA * (NC / 4);

    for (int c = blk; c < NCHUNK; c += BPB) {
        const int aw0 = c * APC + wave * APW;      // this wave's first anchor
        const int a   = aw0 + aloc;                // this lane's anchor (4 lanes share it)

        // ---- issue all global loads up front; meta math runs in their shadow -------
        const float4 an = anchors4[a];
        const f32x4* w4 = cls4b + (size_t)aw0 * (NC / 4);   // wave's 320 float4
        const f32x4 x0 = nt_load4(w4 + lane);
        const f32x4 x1 = nt_load4(w4 + lane + 64);
        const f32x4 x2 = nt_load4(w4 + lane + 128);
        const f32x4 x3 = nt_load4(w4 + lane + 192);
        const f32x4 x4_ = nt_load4(w4 + lane + 256);

        // ---- meta: 8 IoUs per lane, shfl_xor argmax merge over the 4 parts --------
        const float ax1 = an.x, ay1 = an.y, ax2 = an.z, ay2 = an.w;
        const float areaA = (ax2 - ax1) * (ay2 - ay1);

        float best = -1.0f;
        int   arg  = 0;
        #pragma unroll
        for (int i = 0; i < 8; ++i) {
            const int m = part * 8 + i;            // ascending within part -> first-max
            const float bx1 = s_ann[m * 10 + 4];
            const float by1 = s_ann[m * 10 + 5];
            const float bx2 = s_ann[m * 10 + 6];
            const float by2 = s_ann[m * 10 + 7];
            float iw = fminf(ax2, bx2) - fmaxf(ax1, bx1); iw = fmaxf(iw, 0.0f);
            float ih = fminf(ay2, by2) - fmaxf(ay1, by1); ih = fmaxf(ih, 0.0f);
            const float inter = iw * ih;
            const float areaB = (bx2 - bx1) * (by2 - by1);
            const float ua    = fmaxf(areaA + areaB - inter, 1e-8f);
            const float iou   = inter / ua;
            if (iou > best) { best = iou; arg = m; }
        }
        #pragma unroll
        for (int d = 1; d <= 2; d <<= 1) {         // merge parts; tie -> lower index
            const float ob = __shfl_xor(best, d, 64);
            const int   oa = __shfl_xor(arg,  d, 64);
            if (ob > best || (ob == best && oa < arg)) { best = ob; arg = oa; }
        }

        const bool pos = best >= 0.5f;
        const bool neg = best < 0.4f;
        const float coefL = (pos || neg) ? (-0.25f * LN2_) : 0.0f;

        // defer pos-anchor work: LDS queue push only (no global loads in hot loop)
        if (pos && part == 0) {
            const int slot = atomicAdd(&s_qn, 1);
            s_q[slot] = (a << 5) | arg;
        }

        // ---- consume: branch-free neg-term sweep, coef via register shfl -----------
        #define TERM(XV, J)                                                      \
        {                                                                        \
            const int idx = lane + 64 * (J);                                     \
            const float C = __shfl(coefL, (idx / (NC / 4)) << 2, 64);            \
            float p0 = fminf(fmaxf((XV).x, EPS_), 1.0f - EPS_);                  \
            float p1 = fminf(fmaxf((XV).y, EPS_), 1.0f - EPS_);                  \
            float p2 = fminf(fmaxf((XV).z, EPS_), 1.0f - EPS_);                  \
            float p3 = fminf(fmaxf((XV).w, EPS_), 1.0f - EPS_);                  \
            float t0 = p0 * p0 * flog2(1.0f - p0);                               \
            float t1 = p1 * p1 * flog2(1.0f - p1);                               \
            float t2 = p2 * p2 * flog2(1.0f - p2);                               \
            float t3 = p3 * p3 * flog2(1.0f - p3);                               \
            clsSum = fmaf((t0 + t1) + (t2 + t3), C, clsSum);                     \
        }
        TERM(x0, 0) TERM(x1, 1) TERM(x2, 2) TERM(x3, 3) TERM(x4_, 4)
        #undef TERM
    }

    // -------- deferred pos-anchor processing: batched, parallel, off the hot path ---
    __syncthreads();                       // queue pushes + s_qn visible block-wide
    const int qn = s_qn;
    if (tid < qn) {
        const int e = s_q[tid];
        const int a = e >> 5;
        const int m = e & 31;

        const float4 an = anchors4[a];
        const float aw_ = an.z - an.x, ah = an.w - an.y;
        const float acx = an.x + 0.5f * aw_, acy = an.y + 0.5f * ah;

        const int cc = (int)s_ann[m * 10 + 8];
        const float xc = cls[((size_t)b * NA + a) * NC + cc];
        const float p  = fminf(fmaxf(xc, EPS_), 1.0f - EPS_);
        const float q  = 1.0f - p;
        clsSum += 0.75f * q * q * (-LN2_ * flog2(p))
                - 0.25f * p * p * (-LN2_ * flog2(q));

        const float fx1 = s_ann[m * 10 + 4];
        const float fy1 = s_ann[m * 10 + 5];
        const float fx2 = s_ann[m * 10 + 6];
        const float fy2 = s_ann[m * 10 + 7];
        float gw = fx2 - fx1, gh = fy2 - fy1;
        const float gcx = fx1 + 0.5f * gw, gcy = fy1 + 0.5f * gh;  // pre-clip centers
        gw = fmaxf(gw, 1.0f); gh = fmaxf(gh, 1.0f);
        const float t0 = ((gcx - acx) / aw_) * 10.0f;
        const float t1 = ((gcy - acy) / ah)  * 10.0f;
        const float t2 = (LN2_ * flog2(gw / aw_)) * 5.0f;
        const float t3 = (LN2_ * flog2(gh / ah))  * 5.0f;
        const float4 r4 = ((const float4*)reg)[(size_t)(b * NA + a) * 2];
        const float d0 = fabsf(t0 - r4.x);
        const float d1 = fabsf(t1 - r4.y);
        const float d2 = fabsf(t2 - r4.z);
        const float d3 = fabsf(t3 - r4.w);
        const float beta = 1.0f / 9.0f;
        #define SL1(d) ((d) <= beta ? 4.5f * (d) * (d) : (d) - 0.5f / 9.0f)
        regLoss = SL1(d0) + SL1(d1) + SL1(d2) + SL1(d3);
        #undef SL1
    }

    // ---- block reduce -> ONE plain float4 store per block (no atomics, no memset) --
    float rc = wave_reduce_f(clsSum);
    float rr = wave_reduce_f(regLoss);
    if (lane == 0) { s_red[0][wave] = rc; s_red[1][wave] = rr; }
    __syncthreads();
    if (tid == 0) {
        const float cs = (s_red[0][0] + s_red[0][1]) + (s_red[0][2] + s_red[0][3]);
        const float rs = (s_red[1][0] + s_red[1][1]) + (s_red[1][2] + s_red[1][3]);
        partials[blockIdx.x] = make_float4(cs, rs, (float)qn, 0.0f);
    }
}

__global__ __launch_bounds__(BPB)
void focal_finalize(const float4* __restrict__ partials, float* __restrict__ out) {
    __shared__ double s[3][NB][BPB / 64];
    const int tid  = threadIdx.x;          // 512 threads = 8 waves
    const int wave = tid >> 6, lane = tid & 63;
    #pragma unroll
    for (int b = 0; b < NB; ++b) {
        const float4 p = partials[b * BPB + tid];
        const double rc = wave_reduce_d((double)p.x);
        const double rr = wave_reduce_d((double)p.y);
        const double rn = wave_reduce_d((double)p.z);
        if (lane == 0) { s[0][b][wave] = rc; s[1][b][wave] = rr; s[2][b][wave] = rn; }
    }
    __syncthreads();
    if (tid == 0) {
        double clsTot = 0.0, regTot = 0.0;
        #pragma unroll
        for (int b = 0; b < NB; ++b) {
            double C = 0.0, R = 0.0, N = 0.0;
            #pragma unroll
            for (int w = 0; w < BPB / 64; ++w) { C += s[0][b][w]; R += s[1][b][w]; N += s[2][b][w]; }
            const double npc = N < 1.0 ? 1.0 : N;
            clsTot += C / npc;
            regTot += (N > 0.0) ? R / (npc * 4.0) : 0.0;
        }
        out[0] = (float)(clsTot / NB);
        out[1] = (float)(regTot / NB);
    }
}

extern "C" void kernel_launch(void* const* d_in, const int* in_sizes, int n_in,
                              void* d_out, int out_size, void* d_ws, size_t ws_size,
                              hipStream_t stream) {
    const float* cls     = (const float*)d_in[0];   // (B, A, C)
    const float* reg     = (const float*)d_in[1];   // (B, A, 8)
    const float* anchors = (const float*)d_in[2];   // (1, A, 4)
    const float* ann     = (const float*)d_in[3];   // (B, M, 10)
    float* out = (float*)d_out;
    float4* partials = (float4*)d_ws;               // NB*BPB float4 = 32 KB

    focal_persist<<<NB * BPB, BLOCK, 0, stream>>>(cls, reg, anchors, ann, partials);
    focal_finalize<<<1, BPB, 0, stream>>>(partials, out);
}